// Round 2
// baseline (182.115 us; speedup 1.0000x reference)
//
#include <hip/hip_runtime.h>
#include <math.h>

#define N      1000   // NCLASSES
#define NPAD   1024
#define NTH    256

// One block per row. Computes soft_rank at the target index only, then the
// top-K loss contribution, atomically accumulated into d_out[0].
__global__ __launch_bounds__(NTH) void topk_loss_kernel(
    const float* __restrict__ mat, const int* __restrict__ target,
    float* __restrict__ d_out, int nrows)
{
    __shared__ float s[NPAD];        // row values -> sorted descending
    __shared__ float S[NPAD + 1];    // prefix sums of sorted values
    __shared__ float part[NTH];      // scan partials
    __shared__ float rlen[N];        // 1/(len)
    __shared__ float red[NTH];       // min-reduction
    __shared__ int   cnt_sh;

    const int b   = blockIdx.x;
    const int tid = threadIdx.x;
    const float* row = mat + b * N;
    const int   tgt  = target[b];
    const float tval = row[tgt];     // broadcast load

    // ---- load row (pad -inf), build 1/len table ----
    for (int i = tid; i < NPAD; i += NTH)
        s[i] = (i < N) ? row[i] : -INFINITY;
    for (int i = tid; i < N; i += NTH)
        rlen[i] = 1.0f / (float)(i + 1);
    if (tid == 0) cnt_sh = 0;
    __syncthreads();

    // ---- p = stable descending-sort position of the target element ----
    int lc = 0;
    for (int i = tid; i < N; i += NTH) {
        float v = s[i];
        lc += (v > tval) || (v == tval && i < tgt);
    }
    if (lc) atomicAdd(&cnt_sh, lc);
    // (first barrier inside sort loop orders these reads/atomics vs. swaps)

    // ---- bitonic sort, descending ----
    for (unsigned k = 2; k <= NPAD; k <<= 1) {
        for (unsigned j = k >> 1; j > 0; j >>= 1) {
            __syncthreads();
            for (unsigned i = tid; i < NPAD; i += NTH) {
                unsigned ixj = i ^ j;
                if (ixj > i) {
                    float a = s[i], c = s[ixj];
                    bool desc = ((i & k) == 0);
                    if (desc ? (a < c) : (a > c)) { s[i] = c; s[ixj] = a; }
                }
            }
        }
    }
    __syncthreads();

    // zero the -inf pads so scan partials stay finite
    for (int i = N + tid; i < NPAD; i += NTH) s[i] = 0.0f;
    __syncthreads();

    // ---- prefix sum S[0..N] of sorted values (4 elems/thread + scan) ----
    float v0 = s[4 * tid + 0], v1 = s[4 * tid + 1];
    float v2 = s[4 * tid + 2], v3 = s[4 * tid + 3];
    float l1 = v0 + v1, l2 = l1 + v2, l3 = l2 + v3;
    part[tid] = l3;
    __syncthreads();
    for (int off = 1; off < NTH; off <<= 1) {
        float add = (tid >= off) ? part[tid - off] : 0.0f;
        __syncthreads();
        part[tid] += add;
        __syncthreads();
    }
    float base = (tid == 0) ? 0.0f : part[tid - 1];
    if (tid == 0) S[0] = 0.0f;
    S[4 * tid + 1] = base + v0;
    S[4 * tid + 2] = base + l1;
    S[4 * tid + 3] = base + l2;
    S[4 * tid + 4] = base + l3;
    __syncthreads();

    // ---- sol_p = min_{j<=p} max_{k>=p} [(S[k+1]-S[j])/(k-j+1) - n + (j+k)/2]
    const int p = cnt_sh;
    float minv = INFINITY;
    for (int j = tid; j <= p; j += NTH) {
        const float Sj = S[j];
        const float cj = 0.5f * (float)j - (float)N;
        float maxv = -INFINITY;
        #pragma unroll 4
        for (int k = p; k < N; ++k) {
            float m = fmaf(S[k + 1] - Sj, rlen[k - j], cj + 0.5f * (float)k);
            maxv = fmaxf(maxv, m);
        }
        minv = fminf(minv, maxv);
    }
    red[tid] = minv;
    __syncthreads();
    for (int off = NTH >> 1; off > 0; off >>= 1) {
        if (tid < off) red[tid] = fminf(red[tid], red[tid + off]);
        __syncthreads();
    }

    if (tid == 0) {
        float sol        = red[0];
        float rank_label = tval - sol;                   // s[p] == tval exactly
        float loss       = fmaxf(0.0f, 996.0f - rank_label); // N - rank - K + 1
        atomicAdd(d_out, loss / (float)nrows);
    }
}

extern "C" void kernel_launch(void* const* d_in, const int* in_sizes, int n_in,
                              void* d_out, int out_size, void* d_ws, size_t ws_size,
                              hipStream_t stream) {
    (void)n_in; (void)d_ws; (void)ws_size;
    const float* mat    = (const float*)d_in[0];
    const int*   target = (const int*)d_in[1];
    float*       out    = (float*)d_out;
    const int    nrows  = in_sizes[1];   // 64

    hipMemsetAsync(out, 0, sizeof(float) * out_size, stream);
    topk_loss_kernel<<<nrows, NTH, 0, stream>>>(mat, target, out, nrows);
}

// Round 3
// 124.313 us; speedup vs baseline: 1.4650x; 1.4650x over previous
//
#include <hip/hip_runtime.h>
#include <math.h>

#define N      1000   // NCLASSES
#define NPAD   1024
#define NTH    512    // 8 waves/block -> 2 waves/SIMD on the block's CU

// One block per row. Soft-rank at the target index only; loss accumulated
// into d_out[0]. Structure: float4 load -> rank-count -> bitonic sort (1 pair
// per thread per pass) -> shuffle prefix scan -> min-max at position p.
__global__ __launch_bounds__(NTH) void topk_loss_kernel(
    const float* __restrict__ mat, const int* __restrict__ target,
    float* __restrict__ d_out, int nrows)
{
    __shared__ float  s[NPAD];       // row values -> sorted descending
    __shared__ float  S[NPAD + 1];   // prefix sums of sorted values
    __shared__ float2 tab[N];        // {1/(d+1), 0.5*d}
    __shared__ float  wsum[8];       // per-wave scan totals
    __shared__ float  wbase[8];      // exclusive scan of wsum
    __shared__ float  red[8];        // per-wave min
    __shared__ int    cnt_sh;

    const int b    = blockIdx.x;
    const int tid  = threadIdx.x;
    const int lane = tid & 63;
    const int wid  = tid >> 6;
    const float* row = mat + b * N;
    const int   tgt  = target[b];
    const float tval = row[tgt];     // same address all threads -> broadcast

    // ---- load row as float4 (1000 = 250*16B exactly), pad -inf; init tab ----
    if (tid < 250) {
        float4 v = ((const float4*)row)[tid];
        s[4 * tid + 0] = v.x; s[4 * tid + 1] = v.y;
        s[4 * tid + 2] = v.z; s[4 * tid + 3] = v.w;
    } else if (tid < 256) {
        int base = 1000 + (tid - 250) * 4;
        s[base + 0] = -INFINITY; s[base + 1] = -INFINITY;
        s[base + 2] = -INFINITY; s[base + 3] = -INFINITY;
    }
    for (int d = tid; d < N; d += NTH)
        tab[d] = make_float2(1.0f / (float)(d + 1), 0.5f * (float)d);
    if (tid == 0) cnt_sh = 0;
    __syncthreads();

    // ---- p = stable descending-sort position of the target element ----
    {
        float va = s[tid], vb = s[tid + NTH];
        int lc = ((va > tval) || (va == tval && tid < tgt))
               + ((vb > tval) || (vb == tval && (tid + NTH) < tgt));
        // wave reduce then one atomic per wave
        for (int off = 32; off > 0; off >>= 1)
            lc += __shfl_down(lc, off);
        if (lane == 0 && lc) atomicAdd(&cnt_sh, lc);
    }
    // ordered vs sort swaps by the barrier at top of the first sort pass

    // ---- bitonic sort, descending: one compare-exchange per thread/pass ----
    for (unsigned k = 2; k <= NPAD; k <<= 1) {
        for (unsigned j = k >> 1; j > 0; j >>= 1) {
            __syncthreads();
            unsigned i   = ((tid & ~(j - 1)) << 1) | (tid & (j - 1));
            unsigned prt = i | j;
            float a = s[i], c = s[prt];
            bool desc = ((i & k) == 0);
            if (desc ? (a < c) : (a > c)) { s[i] = c; s[prt] = a; }
        }
    }
    __syncthreads();

    // zero the -inf pads (elements 1000..1023) so the scan stays finite
    if (tid >= 488) s[tid + 512] = 0.0f;
    __syncthreads();

    // ---- prefix sum S[0..N]: float2 per thread + shuffle wave scan ----
    float2 v01 = ((const float2*)s)[tid];     // elements 2t, 2t+1
    float  q   = v01.x + v01.y;
    float  incl = q;
    #pragma unroll
    for (int off = 1; off < 64; off <<= 1) {
        float y = __shfl_up(incl, off);
        if (lane >= off) incl += y;
    }
    if (lane == 63) wsum[wid] = incl;
    __syncthreads();
    if (tid == 0) {
        float acc = 0.0f;
        #pragma unroll
        for (int w = 0; w < 8; ++w) { wbase[w] = acc; acc += wsum[w]; }
        S[0] = 0.0f;
    }
    __syncthreads();
    float ex = wbase[wid] + (incl - q);       // exclusive prefix of element 2t
    S[2 * tid + 1] = ex + v01.x;
    S[2 * tid + 2] = ex + q;
    __syncthreads();

    // ---- sol_p = min_{j<=p} [ max_{k>=p} ((S[k+1]-S[j])*tab[k-j].x + tab[k-j].y) + j - N ]
    const int p = cnt_sh;
    const int len = N - p;                    // same trip count for all threads
    float minv = INFINITY;
    for (int j = tid; j <= p; j += NTH) {
        const float  Sj = S[j];
        const float2* tp = &tab[p - j];
        const float*  Sp = &S[p + 1];
        float maxv = -INFINITY;
        #pragma unroll 8
        for (int it = 0; it < len; ++it) {
            float2 tt = tp[it];               // stride-1 b64
            float  m  = fmaf(Sp[it] - Sj, tt.x, tt.y);  // Sp[it]: broadcast
            maxv = fmaxf(maxv, m);
        }
        minv = fminf(minv, maxv + (float)j - (float)N);
    }
    // wave min-reduce, then block reduce over 8 waves
    for (int off = 32; off > 0; off >>= 1)
        minv = fminf(minv, __shfl_down(minv, off));
    if (lane == 0) red[wid] = minv;
    __syncthreads();

    if (tid == 0) {
        float sol = red[0];
        #pragma unroll
        for (int w = 1; w < 8; ++w) sol = fminf(sol, red[w]);
        float rank_label = tval - sol;                    // s_sorted[p] == tval
        float loss       = fmaxf(0.0f, 996.0f - rank_label); // N - rank - K + 1
        atomicAdd(d_out, loss / (float)nrows);
    }
}

extern "C" void kernel_launch(void* const* d_in, const int* in_sizes, int n_in,
                              void* d_out, int out_size, void* d_ws, size_t ws_size,
                              hipStream_t stream) {
    (void)n_in; (void)d_ws; (void)ws_size;
    const float* mat    = (const float*)d_in[0];
    const int*   target = (const int*)d_in[1];
    float*       out    = (float*)d_out;
    const int    nrows  = in_sizes[1];   // 64

    hipMemsetAsync(out, 0, sizeof(float) * out_size, stream);
    topk_loss_kernel<<<nrows, NTH, 0, stream>>>(mat, target, out, nrows);
}

// Round 4
// 119.390 us; speedup vs baseline: 1.5254x; 1.0412x over previous
//
#include <hip/hip_runtime.h>
#include <math.h>

#define N    1000   // NCLASSES
#define NPAD 1024
#define NTH  512    // 8 waves; wave w owns sorted positions [128w, 128w+128)

// One block per row. Soft-rank at the target index only.
// Sort is a hybrid bitonic: registers+shuffles for j<=64, LDS only for j>=128.
__global__ __launch_bounds__(NTH) void topk_loss_kernel(
    const float* __restrict__ mat, const int* __restrict__ target,
    float* __restrict__ d_out, int nrows)
{
    __shared__ float S[NPAD + 1];    // prefix sums of sorted values
    __shared__ float rcp[N];         // 1/(d+1)
    __shared__ float sx[NPAD];       // sort exchange scratch (j>=128 stages)
    __shared__ float wtot[8];        // per-wave scan totals
    __shared__ float red[8];         // per-wave min
    __shared__ int   cnt_sh;

    const int tid  = threadIdx.x;
    const int lane = tid & 63;
    const int w    = tid >> 6;
    const int i0   = (w << 7) + lane;    // position of r0
    const int i1   = i0 + 64;            // position of r1
    const float* row = mat + blockIdx.x * N;
    const int   tgt  = target[blockIdx.x];
    const float tval = row[tgt];         // wave-uniform broadcast load

    // ---- load (coalesced b32 per register), -inf pad; rcp table ----
    float r0 = row[i0];                          // i0 <= 959 < N always
    float r1 = (i1 < N) ? row[i1] : -INFINITY;   // pads live in wave 7's r1
    if (tid == 0) cnt_sh = 0;
    rcp[tid] = 1.0f / (float)(tid + 1);
    if (tid + NTH < N) rcp[tid + NTH] = 1.0f / (float)(tid + NTH + 1);

    // ---- p = stable descending-sort position of target (pre-sort regs) ----
    int lc = ((r0 > tval) || (r0 == tval && i0 < tgt))
           + ((r1 > tval) || (r1 == tval && i1 < tgt));
    #pragma unroll
    for (int off = 32; off; off >>= 1) lc += __shfl_down(lc, off);
    __syncthreads();                     // cnt_sh=0 visible before atomics
    if (lane == 0 && lc) atomicAdd(&cnt_sh, lc);

    // ---- bitonic sort, descending; lower index keeps max iff desc ----
    auto cas_shfl = [&](float& r, int i, unsigned k, unsigned j) {
        float o = __shfl_xor(r, (int)j);         // j <= 32 here
        bool lower = ((lane & (int)j) == 0);
        bool desc  = ((i & (int)k) == 0);
        r = (lower == desc) ? fmaxf(r, o) : fminf(r, o);
    };

    #pragma unroll
    for (unsigned k = 2; k <= 64; k <<= 1) {
        #pragma unroll
        for (unsigned j = k >> 1; j; j >>= 1) {
            cas_shfl(r0, i0, k, j);
            cas_shfl(r1, i1, k, j);
        }
    }
    #pragma unroll
    for (unsigned k = 128; k <= 1024; k <<= 1) {
        #pragma unroll
        for (unsigned j = k >> 1; j >= 128; j >>= 1) {   // LDS stages
            __syncthreads();                 // prior reads done before rewrite
            sx[i0] = r0; sx[i1] = r1;
            __syncthreads();
            float o0 = sx[i0 ^ (int)j], o1 = sx[i1 ^ (int)j];
            bool lower = ((i0 & (int)j) == 0);           // same for i1 (j>=128)
            bool desc  = ((i0 & (int)k) == 0);           // same for i1 (k>=256)
            r0 = (lower == desc) ? fmaxf(r0, o0) : fminf(r0, o0);
            r1 = (lower == desc) ? fmaxf(r1, o1) : fminf(r1, o1);
        }
        {   // j == 64: partner is the other register of the same lane
            bool desc = ((i0 & (int)k) == 0);
            float a = fmaxf(r0, r1), b = fminf(r0, r1);
            r0 = desc ? a : b;
            r1 = desc ? b : a;
        }
        #pragma unroll
        for (unsigned j = 32; j; j >>= 1) {
            cas_shfl(r0, i0, k, j);
            cas_shfl(r1, i1, k, j);
        }
    }

    // ---- prefix sums S[0..N] (shuffle scans; -inf pads -> 0) ----
    if (i1 >= N) r1 = 0.0f;              // sorted: positions >= N hold -inf
    float incl0 = r0;
    #pragma unroll
    for (int off = 1; off < 64; off <<= 1) {
        float y = __shfl_up(incl0, off);
        if (lane >= off) incl0 += y;
    }
    float tot0 = __shfl(incl0, 63);
    float incl1 = r1;
    #pragma unroll
    for (int off = 1; off < 64; off <<= 1) {
        float y = __shfl_up(incl1, off);
        if (lane >= off) incl1 += y;
    }
    if (lane == 63) wtot[w] = incl0 + incl1;
    __syncthreads();
    float base = 0.0f;
    #pragma unroll
    for (int u = 0; u < 8; ++u) {
        float t = wtot[u];
        if (u < w) base += t;
    }
    if (tid == 0) S[0] = 0.0f;
    S[i0 + 1] = base + incl0;
    S[i1 + 1] = base + tot0 + incl1;
    __syncthreads();

    // ---- sol_p = min_{j<=p} max_{k>=p} [(S[k+1]-S[j])/(k-j+1) + (j+k)/2 - N]
    const int p   = cnt_sh;
    const int len = N - p;
    float minv = INFINITY;
    for (int j = tid; j <= p; j += NTH) {
        const float  Sj = S[j];
        const float* Sp = &S[p + 1];         // wave-uniform addr -> broadcast
        const float* rp = &rcp[p - j];       // stride-1 across lanes -> free
        const float  cj = 0.5f * (float)(j + p) - (float)N;
        float maxv = -INFINITY;
        #pragma unroll 8
        for (int it = 0; it < len; ++it) {
            float m = fmaf(Sp[it] - Sj, rp[it], cj + 0.5f * (float)it);
            maxv = fmaxf(maxv, m);
        }
        minv = fminf(minv, maxv);
    }
    #pragma unroll
    for (int off = 32; off; off >>= 1) minv = fminf(minv, __shfl_down(minv, off));
    if (lane == 0) red[w] = minv;
    __syncthreads();

    if (tid == 0) {
        float sol = red[0];
        #pragma unroll
        for (int u = 1; u < 8; ++u) sol = fminf(sol, red[u]);
        float rank_label = tval - sol;                     // s_sorted[p] == tval
        float loss = fmaxf(0.0f, (float)(N - 5 + 1) - rank_label);
        atomicAdd(d_out, loss / (float)nrows);
    }
}

extern "C" void kernel_launch(void* const* d_in, const int* in_sizes, int n_in,
                              void* d_out, int out_size, void* d_ws, size_t ws_size,
                              hipStream_t stream) {
    (void)n_in; (void)d_ws; (void)ws_size;
    const float* mat    = (const float*)d_in[0];
    const int*   target = (const int*)d_in[1];
    float*       out    = (float*)d_out;
    const int    nrows  = in_sizes[1];   // 64

    hipMemsetAsync(out, 0, sizeof(float) * out_size, stream);
    topk_loss_kernel<<<nrows, NTH, 0, stream>>>(mat, target, out, nrows);
}

// Round 5
// 69.632 us; speedup vs baseline: 2.6154x; 1.7146x over previous
//
#include <hip/hip_runtime.h>
#include <math.h>

#define N     1000   // NCLASSES
#define NPAD  1024
#define NTH1  512    // K1: 8 waves; wave w owns sorted positions [128w,128w+128)
#define NTH2  256    // K2: 64 j-lanes x 4 k-quarters
#define MSLICE 16    // K2 blocks per row (64 j each)
#define SROW  1024   // ws row stride (floats) for S

// ---- order-preserving float<->uint for atomicMin ----
__device__ inline unsigned fkey(float x) {
    unsigned u = __float_as_uint(x);
    return (u & 0x80000000u) ? ~u : (u | 0x80000000u);
}
__device__ inline float fdecode(unsigned u) {
    return __uint_as_float((u & 0x80000000u) ? (u & 0x7FFFFFFFu) : ~u);
}

// ===================== K1: sort + prefix-scan + rank ========================
__global__ __launch_bounds__(NTH1) void k1_sort_scan(
    const float* __restrict__ mat, const int* __restrict__ target,
    float* __restrict__ ws)
{
    __shared__ float sx[NPAD];       // exchange scratch for j>=128 stages
    __shared__ float wtot[8];
    __shared__ int   cnt_sh;

    const int tid  = threadIdx.x;
    const int lane = tid & 63;
    const int w    = tid >> 6;
    const int i0   = (w << 7) + lane;
    const int i1   = i0 + 64;
    const int r    = blockIdx.x;
    const float* row = mat + r * N;
    const int   tgt  = target[r];
    const float tval = row[tgt];

    float r0 = row[i0];                          // i0 <= 959 < N
    float r1 = (i1 < N) ? row[i1] : -INFINITY;
    if (tid == 0) cnt_sh = 0;

    // stable descending-sort position of the target
    int lc = ((r0 > tval) || (r0 == tval && i0 < tgt))
           + ((r1 > tval) || (r1 == tval && i1 < tgt));
    #pragma unroll
    for (int off = 32; off; off >>= 1) lc += __shfl_down(lc, off);
    __syncthreads();                             // cnt_sh=0 visible
    if (lane == 0 && lc) atomicAdd(&cnt_sh, lc);

    // bitonic sort, descending (register/shuffle for j<=64, LDS for j>=128)
    auto cas_shfl = [&](float& rr, int i, unsigned k, unsigned j) {
        float o = __shfl_xor(rr, (int)j);
        bool lower = ((lane & (int)j) == 0);
        bool desc  = ((i & (int)k) == 0);
        rr = (lower == desc) ? fmaxf(rr, o) : fminf(rr, o);
    };
    #pragma unroll
    for (unsigned k = 2; k <= 64; k <<= 1)
        #pragma unroll
        for (unsigned j = k >> 1; j; j >>= 1) { cas_shfl(r0, i0, k, j); cas_shfl(r1, i1, k, j); }
    #pragma unroll
    for (unsigned k = 128; k <= 1024; k <<= 1) {
        #pragma unroll
        for (unsigned j = k >> 1; j >= 128; j >>= 1) {
            __syncthreads();
            sx[i0] = r0; sx[i1] = r1;
            __syncthreads();
            float o0 = sx[i0 ^ (int)j], o1 = sx[i1 ^ (int)j];
            bool lower = ((i0 & (int)j) == 0);
            bool desc  = ((i0 & (int)k) == 0);
            r0 = (lower == desc) ? fmaxf(r0, o0) : fminf(r0, o0);
            r1 = (lower == desc) ? fmaxf(r1, o1) : fminf(r1, o1);
        }
        {   // j == 64: in-lane register swap
            bool desc = ((i0 & (int)k) == 0);
            float a = fmaxf(r0, r1), b = fminf(r0, r1);
            r0 = desc ? a : b;
            r1 = desc ? b : a;
        }
        #pragma unroll
        for (unsigned j = 32; j; j >>= 1) { cas_shfl(r0, i0, k, j); cas_shfl(r1, i1, k, j); }
    }

    // prefix sums (shuffle scans); -inf pads -> 0
    if (i1 >= N) r1 = 0.0f;
    float incl0 = r0;
    #pragma unroll
    for (int off = 1; off < 64; off <<= 1) {
        float y = __shfl_up(incl0, off);
        if (lane >= off) incl0 += y;
    }
    float tot0 = __shfl(incl0, 63);
    float incl1 = r1;
    #pragma unroll
    for (int off = 1; off < 64; off <<= 1) {
        float y = __shfl_up(incl1, off);
        if (lane >= off) incl1 += y;
    }
    if (lane == 63) wtot[w] = incl0 + incl1;
    __syncthreads();
    float base = 0.0f;
    #pragma unroll
    for (int u = 0; u < 8; ++u) { float t = wtot[u]; if (u < w) base += t; }

    float* Sg = ws + r * SROW;
    if (tid == 0) Sg[0] = 0.0f;
    Sg[i0 + 1] = base + incl0;
    Sg[i1 + 1] = base + tot0 + incl1;
    if (tid == 0) {
        ((int*)ws)[64 * SROW + r]           = cnt_sh;        // p
        ws[64 * SROW + 64 + r]              = tval;
        ((unsigned*)ws)[64 * SROW + 128 + r] = 0xFFFFFFFFu;  // min sentinel
    }
}

// ===================== K2: min-max at position p ============================
__global__ __launch_bounds__(NTH2) void k2_minmax(
    const float* __restrict__ Sg, const int* __restrict__ pw,
    unsigned* __restrict__ mr)
{
    __shared__ float Sloc[N];    // S[p+1 .. N]
    __shared__ float rtab[N];    // 1/(d+1)
    __shared__ float maxh[NTH2];

    const int r  = blockIdx.y;
    const int m  = blockIdx.x;
    const int t  = threadIdx.x;
    const int p  = pw[r];
    const int j0 = m * 64;
    if (j0 > p) return;
    const int len = N - p;
    const float* Srow = Sg + r * SROW;

    for (int i = t; i < len; i += NTH2) Sloc[i] = Srow[p + 1 + i];
    for (int d = t; d < N; d += NTH2) rtab[d] = 1.0f / (float)(d + 1);
    __syncthreads();

    const int jl = t & 63;
    const int q  = t >> 6;                 // wave-uniform k-quarter
    const int j  = j0 + jl;
    const int k0 = (q * len) >> 2;
    const int k1 = ((q + 1) * len) >> 2;
    float maxv = -INFINITY;
    if (j <= p) {
        const float  Sj = Srow[j];
        const float* sp = &Sloc[k0];       // wave-uniform addr -> broadcast
        const float* rp = &rtab[p + k0 - j];  // stride-1 across lanes
        float c = 0.5f * (float)(j + p + k0) - (float)N;  // (j+k)/2 - N
        #pragma unroll 8
        for (int it = 0; it < k1 - k0; ++it) {
            float mval = fmaf(sp[it] - Sj, rp[it], c);
            maxv = fmaxf(maxv, mval);
            c += 0.5f;                     // exact (halves up to 2^23)
        }
    }
    maxh[t] = maxv;
    __syncthreads();
    if (t < 64) {                          // wave 0: combine quarters, min-reduce
        float mv = fmaxf(fmaxf(maxh[t], maxh[t + 64]),
                         fmaxf(maxh[t + 128], maxh[t + 192]));
        float minv = (j0 + t <= p) ? mv : INFINITY;
        #pragma unroll
        for (int off = 32; off; off >>= 1)
            minv = fminf(minv, __shfl_down(minv, off));
        if (t == 0) atomicMin(&mr[r], fkey(minv));
    }
}

// ===================== K3: loss + mean ======================================
__global__ __launch_bounds__(64) void k3_loss(
    const unsigned* __restrict__ mr, const float* __restrict__ tv,
    float* __restrict__ out, int nrows)
{
    int t = threadIdx.x;
    float loss = 0.0f;
    if (t < nrows) {
        float sol  = fdecode(mr[t]);
        float rank = tv[t] - sol;
        loss = fmaxf(0.0f, (float)(N - 5 + 1) - rank);
    }
    #pragma unroll
    for (int off = 32; off; off >>= 1) loss += __shfl_down(loss, off);
    if (t == 0) out[0] = loss / (float)nrows;
}

// ===================== fallback: monolithic (R4) ============================
__global__ __launch_bounds__(NTH1) void topk_loss_mono(
    const float* __restrict__ mat, const int* __restrict__ target,
    float* __restrict__ d_out, int nrows)
{
    __shared__ float S[NPAD + 1];
    __shared__ float rcp[N];
    __shared__ float sx[NPAD];
    __shared__ float wtot[8];
    __shared__ float red[8];
    __shared__ int   cnt_sh;

    const int tid  = threadIdx.x;
    const int lane = tid & 63;
    const int w    = tid >> 6;
    const int i0   = (w << 7) + lane;
    const int i1   = i0 + 64;
    const float* row = mat + blockIdx.x * N;
    const int   tgt  = target[blockIdx.x];
    const float tval = row[tgt];

    float r0 = row[i0];
    float r1 = (i1 < N) ? row[i1] : -INFINITY;
    if (tid == 0) cnt_sh = 0;
    rcp[tid] = 1.0f / (float)(tid + 1);
    if (tid + NTH1 < N) rcp[tid + NTH1] = 1.0f / (float)(tid + NTH1 + 1);

    int lc = ((r0 > tval) || (r0 == tval && i0 < tgt))
           + ((r1 > tval) || (r1 == tval && i1 < tgt));
    #pragma unroll
    for (int off = 32; off; off >>= 1) lc += __shfl_down(lc, off);
    __syncthreads();
    if (lane == 0 && lc) atomicAdd(&cnt_sh, lc);

    auto cas_shfl = [&](float& rr, int i, unsigned k, unsigned j) {
        float o = __shfl_xor(rr, (int)j);
        bool lower = ((lane & (int)j) == 0);
        bool desc  = ((i & (int)k) == 0);
        rr = (lower == desc) ? fmaxf(rr, o) : fminf(rr, o);
    };
    #pragma unroll
    for (unsigned k = 2; k <= 64; k <<= 1)
        #pragma unroll
        for (unsigned j = k >> 1; j; j >>= 1) { cas_shfl(r0, i0, k, j); cas_shfl(r1, i1, k, j); }
    #pragma unroll
    for (unsigned k = 128; k <= 1024; k <<= 1) {
        #pragma unroll
        for (unsigned j = k >> 1; j >= 128; j >>= 1) {
            __syncthreads();
            sx[i0] = r0; sx[i1] = r1;
            __syncthreads();
            float o0 = sx[i0 ^ (int)j], o1 = sx[i1 ^ (int)j];
            bool lower = ((i0 & (int)j) == 0);
            bool desc  = ((i0 & (int)k) == 0);
            r0 = (lower == desc) ? fmaxf(r0, o0) : fminf(r0, o0);
            r1 = (lower == desc) ? fmaxf(r1, o1) : fminf(r1, o1);
        }
        {
            bool desc = ((i0 & (int)k) == 0);
            float a = fmaxf(r0, r1), b = fminf(r0, r1);
            r0 = desc ? a : b;
            r1 = desc ? b : a;
        }
        #pragma unroll
        for (unsigned j = 32; j; j >>= 1) { cas_shfl(r0, i0, k, j); cas_shfl(r1, i1, k, j); }
    }

    if (i1 >= N) r1 = 0.0f;
    float incl0 = r0;
    #pragma unroll
    for (int off = 1; off < 64; off <<= 1) {
        float y = __shfl_up(incl0, off);
        if (lane >= off) incl0 += y;
    }
    float tot0 = __shfl(incl0, 63);
    float incl1 = r1;
    #pragma unroll
    for (int off = 1; off < 64; off <<= 1) {
        float y = __shfl_up(incl1, off);
        if (lane >= off) incl1 += y;
    }
    if (lane == 63) wtot[w] = incl0 + incl1;
    __syncthreads();
    float base = 0.0f;
    #pragma unroll
    for (int u = 0; u < 8; ++u) { float t = wtot[u]; if (u < w) base += t; }
    if (tid == 0) S[0] = 0.0f;
    S[i0 + 1] = base + incl0;
    S[i1 + 1] = base + tot0 + incl1;
    __syncthreads();

    const int p   = cnt_sh;
    const int len = N - p;
    float minv = INFINITY;
    for (int j = tid; j <= p; j += NTH1) {
        const float  Sj = S[j];
        const float* Sp = &S[p + 1];
        const float* rp = &rcp[p - j];
        const float  cj = 0.5f * (float)(j + p) - (float)N;
        float maxv = -INFINITY;
        #pragma unroll 8
        for (int it = 0; it < len; ++it) {
            float mm = fmaf(Sp[it] - Sj, rp[it], cj + 0.5f * (float)it);
            maxv = fmaxf(maxv, mm);
        }
        minv = fminf(minv, maxv);
    }
    #pragma unroll
    for (int off = 32; off; off >>= 1) minv = fminf(minv, __shfl_down(minv, off));
    if (lane == 0) red[w] = minv;
    __syncthreads();
    if (tid == 0) {
        float sol = red[0];
        #pragma unroll
        for (int u = 1; u < 8; ++u) sol = fminf(sol, red[u]);
        float rank_label = tval - sol;
        float loss = fmaxf(0.0f, (float)(N - 5 + 1) - rank_label);
        atomicAdd(d_out, loss / (float)nrows);
    }
}

extern "C" void kernel_launch(void* const* d_in, const int* in_sizes, int n_in,
                              void* d_out, int out_size, void* d_ws, size_t ws_size,
                              hipStream_t stream) {
    (void)n_in;
    const float* mat    = (const float*)d_in[0];
    const int*   target = (const int*)d_in[1];
    float*       out    = (float*)d_out;
    const int    nrows  = in_sizes[1];   // 64

    const size_t need = (size_t)(64 * SROW + 192) * sizeof(float);
    if (nrows == 64 && ws_size >= need) {
        float*    ws = (float*)d_ws;
        float*    Sg = ws;
        int*      pw = (int*)(ws + 64 * SROW);
        float*    tv = ws + 64 * SROW + 64;
        unsigned* mr = (unsigned*)(ws + 64 * SROW + 128);
        k1_sort_scan<<<nrows, NTH1, 0, stream>>>(mat, target, ws);
        dim3 g2(MSLICE, nrows);
        k2_minmax<<<g2, NTH2, 0, stream>>>(Sg, pw, mr);
        k3_loss<<<1, 64, 0, stream>>>(mr, tv, out, nrows);
    } else {
        hipMemsetAsync(out, 0, sizeof(float) * out_size, stream);
        topk_loss_mono<<<nrows, NTH1, 0, stream>>>(mat, target, out, nrows);
    }
}